// Round 12
// baseline (381.927 us; speedup 1.0000x reference)
//
#include <hip/hip_runtime.h>
#include <hip/hip_bf16.h>

typedef __hip_bfloat16 bf16;
typedef short bf16x8 __attribute__((ext_vector_type(8)));
typedef float f32x4 __attribute__((ext_vector_type(4)));

__device__ __forceinline__ float2 bfpair(unsigned u){
  float2 r; r.x = __uint_as_float(u<<16); r.y = __uint_as_float(u & 0xffff0000u); return r;
}
__device__ __forceinline__ float bfu(unsigned short u){ return __uint_as_float(((unsigned)u)<<16); }
__device__ __forceinline__ unsigned f2bf(float f){
  unsigned u = __float_as_uint(f);
  return (u + 0x7fffu + ((u>>16)&1u)) >> 16;
}
__device__ __forceinline__ unsigned fpack(float a, float b){
  return (f2bf(b)<<16) | f2bf(a);
}
__device__ __forceinline__ int edge_is64(const int* e){
  return (e[1]==0) & (e[3]==0) & (e[5]==0);
}
__device__ __forceinline__ int edge_ld(const int* e, int is64, int idx){
  return e[is64 ? 2*idx : idx];
}

// ---------------- fused prologue: degree histogram + ratio + all weight swizzles ----
__global__ void k_pre(const float* __restrict__ x, const int* __restrict__ eidx,
                      unsigned* __restrict__ ratio, int* __restrict__ deg,
                      int N, int E, int nbE,
                      const float* __restrict__ llW, const float* __restrict__ lrW,
                      const float* __restrict__ dW1, const float* __restrict__ sW1,
                      const float* __restrict__ dW2, const float* __restrict__ sW2,
                      const float* __restrict__ eW2,
                      unsigned short* __restrict__ WTs, unsigned short* __restrict__ WT1,
                      unsigned short* __restrict__ WT2, unsigned short* __restrict__ WE2){
  int b = (int)blockIdx.x;
  if(b < nbE){
    int e = b*256 + threadIdx.x;
    if(e>=E) return;
    int is64 = edge_is64(eidx);
    int d = edge_ld(eidx, is64, E+e);
    if((unsigned)d < (unsigned)N) atomicAdd(&deg[d], 1);
    return;
  }
  if(b < nbE + 256){
    int i = (b-nbE)*256 + threadIdx.x;
    int stride = 256*256;
    float m = 0.f;
    for(; i<N; i+=stride){
      float a = x[(size_t)i*12+3];
      float bb = x[(size_t)i*12+4];
      float c = x[(size_t)i*12+5];
      m = fmaxf(m, sqrtf(a*a+bb*bb+c*c));
    }
    #pragma unroll
    for(int off=1; off<64; off<<=1) m = fmaxf(m, __shfl_xor(m, off));
    if((threadIdx.x & 63)==0) atomicMax(ratio, __float_as_uint(m));
    return;
  }
  int idx = (b - nbE - 256)*256 + threadIdx.x;   // 196608 total
  int j = idx & 7;
  int lane = (idx>>3) & 63;
  int q = lane >> 4, p = lane & 15;
  if(idx < 131072){
    int nt = (idx>>9) & 7, ks = (idx>>12) & 7, l = (idx>>15) & 3;
    int k = ks*32 + q*8 + j, n = nt*16 + p;
    float v = (k<128) ? llW[(size_t)l*16384 + (size_t)k*128 + n]
                      : lrW[(size_t)l*16384 + (size_t)(k-128)*128 + n];
    WTs[idx] = (unsigned short)f2bf(v);
  } else if(idx < 163840){
    int i2 = idx - 131072;
    int nt = (i2>>9) & 15, ks = (i2>>13) & 3;
    int k = ks*32 + q*8 + j, n = nt*16 + p;
    float v = (n<128) ? dW1[(size_t)k*128 + n] : sW1[(size_t)k*128 + (n-128)];
    WT1[i2] = (unsigned short)f2bf(v);
  } else if(idx < 180224){
    int i2 = idx - 163840;
    int nt = (i2>>9) & 7, ks = (i2>>12) & 3;
    int k = ks*32 + q*8 + j, n = nt*16 + p;
    float v = (n<64) ? dW2[(size_t)k*64 + n] : sW2[(size_t)k*64 + (n-64)];
    WT2[i2] = (unsigned short)f2bf(v);
  } else if(idx < 196608){
    int i2 = idx - 180224;
    int nt = (i2>>9) & 7, ks = (i2>>12) & 3;
    int k = ks*32 + q*8 + j, n = nt*16 + p;
    WE2[i2] = (unsigned short)f2bf(eW2[(size_t)k*128 + n]);
  }
}

// ---------------- scan over deg[N] ----------------
__global__ void k_scan1(const int* __restrict__ deg, int* __restrict__ bsum, int N){
  int t = threadIdx.x;
  int idx0 = blockIdx.x*1024 + t*4;
  int s=0;
  #pragma unroll
  for(int i=0;i<4;i++){ int idx=idx0+i; if(idx<N) s += deg[idx]; }
  #pragma unroll
  for(int off=1; off<64; off<<=1) s += __shfl_xor(s, off);
  __shared__ int ws4[4];
  if((t&63)==0) ws4[t>>6]=s;
  __syncthreads();
  if(t==0) bsum[blockIdx.x]=ws4[0]+ws4[1]+ws4[2]+ws4[3];
}
// scan3 with inlined scan-of-block-sums (nb <= 64)
__global__ void k_scan3(const int* __restrict__ deg, const int* __restrict__ bsum,
                        int* __restrict__ offs, int* __restrict__ pos,
                        float* __restrict__ invdeg, int N, int E, int nb){
  __shared__ int sb[64];
  int t = threadIdx.x;
  if(t < 64){
    int v = (t<nb)? bsum[t] : 0;
    int incl = v;
    #pragma unroll
    for(int off=1; off<64; off<<=1){ int u = __shfl_up(incl, (unsigned)off); if(t>=off) incl+=u; }
    sb[t] = incl - v;   // exclusive
  }
  __syncthreads();
  int idx0 = blockIdx.x*1024 + t*4;
  int d[4]; int s=0;
  #pragma unroll
  for(int i=0;i<4;i++){ int idx=idx0+i; d[i] = (idx<N)? deg[idx]:0; s+=d[i]; }
  int lane=t&63, w=t>>6;
  int incl=s;
  #pragma unroll
  for(int off=1; off<64; off<<=1){ int v=__shfl_up(incl, (unsigned)off); if(lane>=off) incl+=v; }
  __shared__ int wsum[4];
  if(lane==63) wsum[w]=incl;
  __syncthreads();
  int base = sb[blockIdx.x];
  for(int i=0;i<w;i++) base += wsum[i];
  int run = base + incl - s;
  #pragma unroll
  for(int i=0;i<4;i++){
    int idx=idx0+i;
    if(idx<N){
      offs[idx]=run; pos[idx]=run;
      invdeg[idx] = 1.0f / (float)(d[i]>0? d[i]:1);
    }
    run += d[i];
  }
  if(blockIdx.x==0 && t==0) offs[N]=E;
}

// ---------------- encoder (blocks [0,nbTile)) + CSR bucket (rest), merged ----------
__global__ __launch_bounds__(256) void k_enc_bucket(
  const float* __restrict__ x,
  const float* __restrict__ W1, const float* __restrict__ b1,
  const unsigned short* __restrict__ WE2, const float* __restrict__ b2,
  bf16* __restrict__ h, int N, int nbTile,
  const int* __restrict__ eidx, int* __restrict__ pos, int* __restrict__ csr, int E)
{
  if((int)blockIdx.x >= nbTile){
    int e = ((int)blockIdx.x - nbTile)*256 + threadIdx.x;
    if(e>=E) return;
    int is64 = edge_is64(eidx);
    int d = edge_ld(eidx, is64, E+e);
    int s = edge_ld(eidx, is64, e);
    if((unsigned)d >= (unsigned)N) return;
    if((unsigned)s >= (unsigned)N) s = 0;
    int p = atomicAdd(&pos[d], 1);
    if((unsigned)p < (unsigned)E) csr[p] = s;
    return;
  }
  __shared__ float Xs[64][12];
  __shared__ float W1s[12][128];
  __shared__ float b1s[128];
  __shared__ __align__(16) unsigned short T1b[64][136];
  int tid = threadIdx.x;
  int tx = tid & 31, ty = tid >> 5;
  int rowBase = blockIdx.x*64;
  for(int idx=tid; idx<768; idx+=256){
    int r = idx/12, c = idx - r*12;
    int row = rowBase + r;
    Xs[r][c] = (row<N)? x[(size_t)row*12+c] : 0.f;
  }
  for(int idx=tid; idx<1536; idx+=256) W1s[idx>>7][idx&127] = W1[idx];
  if(tid<128) b1s[tid] = b1[tid];
  __syncthreads();
  float acc[8][4] = {};
  #pragma unroll
  for(int k=0;k<12;k++){
    float4 w4 = *(float4*)&W1s[k][tx*4];
    #pragma unroll
    for(int r=0;r<8;r++){
      float a = Xs[ty*8+r][k];
      acc[r][0]+=a*w4.x; acc[r][1]+=a*w4.y; acc[r][2]+=a*w4.z; acc[r][3]+=a*w4.w;
    }
  }
  #pragma unroll
  for(int r=0;r<8;r++)
    #pragma unroll
    for(int c=0;c<4;c++)
      T1b[ty*8+r][tx*4+c] = (unsigned short)f2bf(fmaxf(acc[r][c] + b1s[tx*4+c], 0.f));
  __syncthreads();

  int lane = tid & 63;
  int w = tid >> 6, q = lane >> 4, p = lane & 15;
  f32x4 acc2[8];
  #pragma unroll
  for(int nt=0; nt<8; nt++) acc2[nt] = (f32x4){0.f,0.f,0.f,0.f};
  #pragma unroll
  for(int ks=0; ks<4; ks++){
    bf16x8 af = *(const bf16x8*)&T1b[w*16+p][ks*32+q*8];
    #pragma unroll
    for(int nt=0; nt<8; nt++){
      bf16x8 bfr = *(const bf16x8*)(WE2 + ((size_t)(ks*8+nt)*64 + lane)*8);
      acc2[nt] = __builtin_amdgcn_mfma_f32_16x16x32_bf16(af, bfr, acc2[nt], 0,0,0);
    }
  }
  float b2v[8];
  #pragma unroll
  for(int nt=0; nt<8; nt++) b2v[nt] = b2[nt*16+p];
  unsigned short* hu = (unsigned short*)h;
  #pragma unroll
  for(int r=0;r<4;r++){
    int row = rowBase + w*16 + q*4 + r;
    if(row < N){
      #pragma unroll
      for(int nt=0; nt<8; nt++)
        hu[(size_t)row*128 + nt*16+p] = (unsigned short)f2bf(acc2[nt][r] + b2v[nt]);
    }
  }
}

// ---------------- fused SAGE layer, 32 rows/block with B-frag reuse ---------------
// Phase 1: 16 quarter-waves; each gathers 2 rows (rloc, rloc+16) into 8.5 KB LDS.
// Phase 2: wave w handles n-tiles (2w,2w+1) x m-tiles {0,1}; each B-frag loaded
//          once, used by 2 MFMAs -> halves WT L2 traffic vs 16-row version.
__global__ __launch_bounds__(256) void k_layer32(
    const bf16* __restrict__ hin, bf16* __restrict__ hout,
    const int* __restrict__ offs, const int* __restrict__ csr,
    const float* __restrict__ invdeg,
    const unsigned short* __restrict__ WT,   // swizzled frags [ks8][nt8][64][8]
    const float* __restrict__ bl, const float* __restrict__ lng,
    const float* __restrict__ lnb, int N, int E)
{
  __shared__ __align__(16) unsigned short Ag[32][136];
  __shared__ float sPart[4][32];
  __shared__ float qPart[4][32];
  int tid = threadIdx.x;
  int rowBase = blockIdx.x*32;

  // ---- phase 1: gather-aggregate, 2 rows per quarter-wave ----
  {
    int qw = tid >> 4;          // 0..15
    int l  = tid & 15;
    #pragma unroll
    for(int rr=0; rr<2; rr++){
      int rloc = qw + rr*16;
      int row = rowBase + rloc;
      float a0=0.f,a1=0.f,a2=0.f,a3=0.f,a4=0.f,a5=0.f,a6=0.f,a7=0.f;
      if(row < N){
        int s = offs[row], e = offs[row+1];
        s = max(0, min(s, E)); e = max(s, min(e, E));
        int i = s;
        for(; i+4<=e; i+=4){
          int j0=csr[i], j1=csr[i+1], j2=csr[i+2], j3=csr[i+3];
          uint4 u0 = *(const uint4*)(hin + (size_t)j0*128 + l*8);
          uint4 u1 = *(const uint4*)(hin + (size_t)j1*128 + l*8);
          uint4 u2 = *(const uint4*)(hin + (size_t)j2*128 + l*8);
          uint4 u3 = *(const uint4*)(hin + (size_t)j3*128 + l*8);
          float2 f;
          f=bfpair(u0.x); a0+=f.x; a1+=f.y;  f=bfpair(u0.y); a2+=f.x; a3+=f.y;
          f=bfpair(u0.z); a4+=f.x; a5+=f.y;  f=bfpair(u0.w); a6+=f.x; a7+=f.y;
          f=bfpair(u1.x); a0+=f.x; a1+=f.y;  f=bfpair(u1.y); a2+=f.x; a3+=f.y;
          f=bfpair(u1.z); a4+=f.x; a5+=f.y;  f=bfpair(u1.w); a6+=f.x; a7+=f.y;
          f=bfpair(u2.x); a0+=f.x; a1+=f.y;  f=bfpair(u2.y); a2+=f.x; a3+=f.y;
          f=bfpair(u2.z); a4+=f.x; a5+=f.y;  f=bfpair(u2.w); a6+=f.x; a7+=f.y;
          f=bfpair(u3.x); a0+=f.x; a1+=f.y;  f=bfpair(u3.y); a2+=f.x; a3+=f.y;
          f=bfpair(u3.z); a4+=f.x; a5+=f.y;  f=bfpair(u3.w); a6+=f.x; a7+=f.y;
        }
        for(; i<e; ++i){
          int jj = csr[i];
          uint4 u = *(const uint4*)(hin + (size_t)jj*128 + l*8);
          float2 f;
          f=bfpair(u.x); a0+=f.x; a1+=f.y;  f=bfpair(u.y); a2+=f.x; a3+=f.y;
          f=bfpair(u.z); a4+=f.x; a5+=f.y;  f=bfpair(u.w); a6+=f.x; a7+=f.y;
        }
        float id = invdeg[row];
        a0*=id; a1*=id; a2*=id; a3*=id; a4*=id; a5*=id; a6*=id; a7*=id;
      }
      uint4 o;
      o.x = fpack(a0,a1); o.y = fpack(a2,a3);
      o.z = fpack(a4,a5); o.w = fpack(a6,a7);
      *(uint4*)&Ag[rloc][l*8] = o;
    }
  }
  __syncthreads();

  // ---- phase 2: y = [agg|hin] @ Wcat + bl for 32 rows ----
  int lane = tid & 63;
  int w = tid >> 6;            // wave 0..3 -> n-tiles 2w, 2w+1
  int q = lane >> 4;
  int p = lane & 15;
  int nt0 = 2*w, nt1 = 2*w+1;
  int am0 = rowBase + p;
  int am1 = rowBase + 16 + p;
  bool ok0 = am0 < N, ok1 = am1 < N;
  const unsigned short* hRow0 = (const unsigned short*)hin + (size_t)am0*128;
  const unsigned short* hRow1 = (const unsigned short*)hin + (size_t)am1*128;

  f32x4 a00 = (f32x4){0.f,0.f,0.f,0.f};   // mtile0 x nt0
  f32x4 a01 = (f32x4){0.f,0.f,0.f,0.f};   // mtile0 x nt1
  f32x4 a10 = (f32x4){0.f,0.f,0.f,0.f};   // mtile1 x nt0
  f32x4 a11 = (f32x4){0.f,0.f,0.f,0.f};   // mtile1 x nt1
  #pragma unroll
  for(int ks=0; ks<8; ks++){
    bf16x8 af0, af1;
    if(ks < 4){
      af0 = *(const bf16x8*)&Ag[p][ks*32 + q*8];
      af1 = *(const bf16x8*)&Ag[16+p][ks*32 + q*8];
    } else {
      af0 = (bf16x8){0,0,0,0,0,0,0,0};
      af1 = (bf16x8){0,0,0,0,0,0,0,0};
      if(ok0) af0 = *(const bf16x8*)(hRow0 + (ks-4)*32 + q*8);
      if(ok1) af1 = *(const bf16x8*)(hRow1 + (ks-4)*32 + q*8);
    }
    bf16x8 b0 = *(const bf16x8*)(WT + ((size_t)(ks*8+nt0)*64 + lane)*8);
    bf16x8 b1 = *(const bf16x8*)(WT + ((size_t)(ks*8+nt1)*64 + lane)*8);
    a00 = __builtin_amdgcn_mfma_f32_16x16x32_bf16(af0, b0, a00, 0,0,0);
    a01 = __builtin_amdgcn_mfma_f32_16x16x32_bf16(af0, b1, a01, 0,0,0);
    a10 = __builtin_amdgcn_mfma_f32_16x16x32_bf16(af1, b0, a10, 0,0,0);
    a11 = __builtin_amdgcn_mfma_f32_16x16x32_bf16(af1, b1, a11, 0,0,0);
  }

  // bias + per-wave partial LN sums
  int c0 = nt0*16 + p, c1 = nt1*16 + p;
  float bl0 = bl[c0], g0 = lng[c0], lb0 = lnb[c0];
  float bl1 = bl[c1], g1 = lng[c1], lb1 = lnb[c1];
  float y00[4], y01[4], y10[4], y11[4];
  #pragma unroll
  for(int r=0;r<4;r++){
    y00[r] = a00[r] + bl0;  y01[r] = a01[r] + bl1;
    y10[r] = a10[r] + bl0;  y11[r] = a11[r] + bl1;
    float s0  = y00[r] + y01[r];
    float sq0 = y00[r]*y00[r] + y01[r]*y01[r];
    float s1  = y10[r] + y11[r];
    float sq1 = y10[r]*y10[r] + y11[r]*y11[r];
    #pragma unroll
    for(int off=1; off<16; off<<=1){
      s0 += __shfl_xor(s0, off); sq0 += __shfl_xor(sq0, off);
      s1 += __shfl_xor(s1, off); sq1 += __shfl_xor(sq1, off);
    }
    if(p==0){
      sPart[w][q*4+r] = s0;     qPart[w][q*4+r] = sq0;
      sPart[w][16+q*4+r] = s1;  qPart[w][16+q*4+r] = sq1;
    }
  }
  __syncthreads();

  // totals, LN, residual-ReLU, store (both m-tiles)
  const unsigned short* hiu = (const unsigned short*)hin;
  unsigned short* hou = (unsigned short*)hout;
  #pragma unroll
  for(int mt=0; mt<2; mt++){
    #pragma unroll
    for(int r=0;r<4;r++){
      int rloc = mt*16 + q*4 + r;
      float s  = sPart[0][rloc]+sPart[1][rloc]+sPart[2][rloc]+sPart[3][rloc];
      float sq = qPart[0][rloc]+qPart[1][rloc]+qPart[2][rloc]+qPart[3][rloc];
      float mu = s*(1.f/128.f);
      float var = fmaxf(sq*(1.f/128.f) - mu*mu, 0.f);
      float rstd = rsqrtf(var + 1e-5f);
      int row = rowBase + rloc;
      if(row < N){
        float yv0 = mt ? y10[r] : y00[r];
        float yv1 = mt ? y11[r] : y01[r];
        float h0 = bfu(hiu[(size_t)row*128 + c0]);
        float h1 = bfu(hiu[(size_t)row*128 + c1]);
        float o0 = h0 + fmaxf((yv0-mu)*rstd*g0 + lb0, 0.f);
        float o1 = h1 + fmaxf((yv1-mu)*rstd*g1 + lb1, 0.f);
        hou[(size_t)row*128 + c0] = (unsigned short)f2bf(o0);
        hou[(size_t)row*128 + c1] = (unsigned short)f2bf(o1);
      }
    }
  }
}

// ---------------- fused both-heads via MFMA, swizzled B frags ----------------
__global__ __launch_bounds__(256) void k_heads_mfma(
  const bf16* __restrict__ h,
  const unsigned short* __restrict__ WT1,  // [ks4][nt16][64][8]
  const unsigned short* __restrict__ WT2,  // [ks4][nt8][64][8]
  const float* __restrict__ db1, const float* __restrict__ sb1,
  const float* __restrict__ db2, const float* __restrict__ sb2,
  const float* __restrict__ dW3, const float* __restrict__ db3,
  const float* __restrict__ sW3, const float* __restrict__ sb3,
  const float* __restrict__ ratio_p, float* __restrict__ out, int N)
{
  __shared__ __align__(16) unsigned short T1s[4][16][264];
  const float ratio = *ratio_p;
  int tid = threadIdx.x;
  int lane = tid & 63;
  int w = tid >> 6;
  int q = lane >> 4;
  int p = lane & 15;
  int rowBase = blockIdx.x*64;
  int am = rowBase + w*16 + p;
  bool arow_ok = am < N;
  const unsigned short* hRow = (const unsigned short*)h + (size_t)am*128;

  f32x4 acc1[16];
  #pragma unroll
  for(int nt=0; nt<16; nt++) acc1[nt] = (f32x4){0.f,0.f,0.f,0.f};
  #pragma unroll
  for(int ks=0; ks<4; ks++){
    int koff = ks*32 + q*8;
    bf16x8 af = {0,0,0,0,0,0,0,0};
    if(arow_ok) af = *(const bf16x8*)(hRow + koff);
    #pragma unroll
    for(int nt=0; nt<16; nt++){
      bf16x8 bfr = *(const bf16x8*)(WT1 + ((size_t)(ks*16+nt)*64 + lane)*8);
      acc1[nt] = __builtin_amdgcn_mfma_f32_16x16x32_bf16(af, bfr, acc1[nt], 0,0,0);
    }
  }
  #pragma unroll
  for(int nt=0; nt<16; nt++){
    float b1v = (nt<8) ? db1[nt*16+p] : sb1[(nt-8)*16+p];
    #pragma unroll
    for(int r=0;r<4;r++){
      float v = fmaxf(acc1[nt][r] + b1v, 0.f);
      T1s[w][q*4+r][nt*16+p] = (unsigned short)f2bf(v);
    }
  }
  __syncthreads();

  f32x4 acc2[8];
  #pragma unroll
  for(int nt=0; nt<8; nt++) acc2[nt] = (f32x4){0.f,0.f,0.f,0.f};
  #pragma unroll
  for(int ks=0; ks<4; ks++){
    int koff = ks*32 + q*8;
    bf16x8 ad = *(const bf16x8*)&T1s[w][p][koff];
    bf16x8 as = *(const bf16x8*)&T1s[w][p][128+koff];
    #pragma unroll
    for(int nt=0; nt<8; nt++){
      bf16x8 bfr = *(const bf16x8*)(WT2 + ((size_t)(ks*8+nt)*64 + lane)*8);
      acc2[nt] = __builtin_amdgcn_mfma_f32_16x16x32_bf16(nt<4? ad : as, bfr, acc2[nt], 0,0,0);
    }
  }

  float w3d[4][3], w3s[4], bd2[4], bs2[4];
  #pragma unroll
  for(int nt=0; nt<4; nt++){
    #pragma unroll
    for(int c=0;c<3;c++) w3d[nt][c] = dW3[(nt*16+p)*3 + c];
    w3s[nt] = sW3[nt*16+p];
    bd2[nt] = db2[nt*16+p];
    bs2[nt] = sb2[nt*16+p];
  }
  float b3v = (p==0)? db3[0] : (p==1)? db3[1] : (p==2)? db3[2] : sb3[0];
  #pragma unroll
  for(int r=0;r<4;r++){
    int row = rowBase + w*16 + q*4 + r;
    float pd0=0.f, pd1=0.f, pd2=0.f, ps=0.f;
    #pragma unroll
    for(int nt=0; nt<4; nt++){
      float td = fmaxf(acc2[nt][r]   + bd2[nt], 0.f);
      float ts = fmaxf(acc2[nt+4][r] + bs2[nt], 0.f);
      pd0 += td*w3d[nt][0]; pd1 += td*w3d[nt][1]; pd2 += td*w3d[nt][2];
      ps  += ts*w3s[nt];
    }
    #pragma unroll
    for(int off=1; off<16; off<<=1){
      pd0 += __shfl_xor(pd0, off); pd1 += __shfl_xor(pd1, off);
      pd2 += __shfl_xor(pd2, off); ps  += __shfl_xor(ps, off);
    }
    if(row < N && p < 4){
      float v = (p==0)? pd0 : (p==1)? pd1 : (p==2)? pd2 : ps;
      out[(size_t)row*4 + p] = (v + b3v)*ratio;
    }
  }
}

extern "C" void kernel_launch(void* const* d_in, const int* in_sizes, int n_in,
                              void* d_out, int out_size, void* d_ws, size_t ws_size,
                              hipStream_t stream)
{
  const float* x   = (const float*)d_in[0];
  const int*  eidx = (const int*) d_in[1];
  const float* eW1 = (const float*)d_in[2];
  const float* eb1 = (const float*)d_in[3];
  const float* eW2 = (const float*)d_in[4];
  const float* eb2 = (const float*)d_in[5];
  const float* llW = (const float*)d_in[6];
  const float* llb = (const float*)d_in[7];
  const float* lrW = (const float*)d_in[8];
  const float* lng = (const float*)d_in[9];
  const float* lnb = (const float*)d_in[10];
  const float* dW1 = (const float*)d_in[11];
  const float* db1 = (const float*)d_in[12];
  const float* dW2 = (const float*)d_in[13];
  const float* db2 = (const float*)d_in[14];
  const float* dW3 = (const float*)d_in[15];
  const float* db3 = (const float*)d_in[16];
  const float* sW1 = (const float*)d_in[17];
  const float* sb1 = (const float*)d_in[18];
  const float* sW2 = (const float*)d_in[19];
  const float* sb2 = (const float*)d_in[20];
  const float* sW3 = (const float*)d_in[21];
  const float* sb3 = (const float*)d_in[22];
  float* out = (float*)d_out;

  const int N = in_sizes[0] / 12;
  const int E = in_sizes[1] / 2;
  (void)n_in; (void)out_size; (void)ws_size;

  char* base = (char*)d_ws;
  size_t off = 0;
  auto alloc = [&](size_t nbytes)->char*{
    char* p = base + off; off += (nbytes + 255) & ~(size_t)255; return p;
  };
  unsigned* ratio = (unsigned*)alloc(4);
  int*   deg    = (int*)  alloc((size_t)N*4);
  int*   offs   = (int*)  alloc(((size_t)N+1)*4);
  int*   pos    = (int*)  alloc((size_t)N*4);
  int*   bsum   = (int*)  alloc(256*4);
  int*   csr    = (int*)  alloc((size_t)E*4);
  float* invdeg = (float*)alloc((size_t)N*4);
  bf16*  hA     = (bf16*) alloc((size_t)N*128*2);
  bf16*  hB     = (bf16*) alloc((size_t)N*128*2);
  unsigned short* WTs  = (unsigned short*)alloc((size_t)131072*2);
  unsigned short* WT1h = (unsigned short*)alloc((size_t)32768*2);
  unsigned short* WT2h = (unsigned short*)alloc((size_t)16384*2);
  unsigned short* WE2  = (unsigned short*)alloc((size_t)16384*2);

  size_t zbytes = (size_t)((char*)offs - base);   // zero ratio + deg
  hipMemsetAsync(d_ws, 0, zbytes, stream);

  int nbE    = (E + 255)/256;
  int nbScan = (N + 1023)/1024;
  int nbTile = (N + 63)/64;
  int nbLay  = (N + 31)/32;

  k_pre  <<<nbE + 256 + 768, 256, 0, stream>>>(x, eidx, ratio, deg, N, E, nbE,
      llW, lrW, dW1, sW1, dW2, sW2, eW2, WTs, WT1h, WT2h, WE2);
  k_scan1<<<nbScan, 256, 0, stream>>>(deg, bsum, N);
  k_scan3<<<nbScan, 256, 0, stream>>>(deg, bsum, offs, pos, invdeg, N, E, nbScan);
  k_enc_bucket<<<nbTile + nbE, 256, 0, stream>>>(x, eW1, eb1, WE2, eb2, hA, N, nbTile,
      eidx, pos, csr, E);

  bf16* hin = hA; bf16* hout = hB;
  for(int l=0;l<4;l++){
    k_layer32<<<nbLay, 256, 0, stream>>>(hin, hout, offs, csr, invdeg,
        WTs + (size_t)l*32768,
        llb + (size_t)l*128, lng + (size_t)l*128, lnb + (size_t)l*128, N, E);
    bf16* t = hin; hin = hout; hout = t;
  }
  // after 4 swaps, final h is in hA (hin)
  k_heads_mfma<<<nbTile, 256, 0, stream>>>(hin, WT1h, WT2h,
      db1, sb1, db2, sb2, dW3, db3, sW3, sb3, (const float*)ratio, out, N);
}

// Round 13
// 340.961 us; speedup vs baseline: 1.1201x; 1.1201x over previous
//
#include <hip/hip_runtime.h>
#include <hip/hip_bf16.h>

typedef __hip_bfloat16 bf16;
typedef short bf16x8 __attribute__((ext_vector_type(8)));
typedef float f32x4 __attribute__((ext_vector_type(4)));

__device__ __forceinline__ float2 bfpair(unsigned u){
  float2 r; r.x = __uint_as_float(u<<16); r.y = __uint_as_float(u & 0xffff0000u); return r;
}
__device__ __forceinline__ float bfu(unsigned short u){ return __uint_as_float(((unsigned)u)<<16); }
__device__ __forceinline__ unsigned f2bf(float f){
  unsigned u = __float_as_uint(f);
  return (u + 0x7fffu + ((u>>16)&1u)) >> 16;
}
__device__ __forceinline__ unsigned fpack(float a, float b){
  return (f2bf(b)<<16) | f2bf(a);
}
__device__ __forceinline__ int edge_is64(const int* e){
  return (e[1]==0) & (e[3]==0) & (e[5]==0);
}
__device__ __forceinline__ int edge_ld(const int* e, int is64, int idx){
  return e[is64 ? 2*idx : idx];
}

// ---------------- fused prologue: degree histogram + ratio + all weight swizzles ----
__global__ void k_pre(const float* __restrict__ x, const int* __restrict__ eidx,
                      unsigned* __restrict__ ratio, int* __restrict__ deg,
                      int N, int E, int nbE,
                      const float* __restrict__ llW, const float* __restrict__ lrW,
                      const float* __restrict__ dW1, const float* __restrict__ sW1,
                      const float* __restrict__ dW2, const float* __restrict__ sW2,
                      const float* __restrict__ eW2,
                      unsigned short* __restrict__ WTs, unsigned short* __restrict__ WT1,
                      unsigned short* __restrict__ WT2, unsigned short* __restrict__ WE2){
  int b = (int)blockIdx.x;
  if(b < nbE){
    int e = b*256 + threadIdx.x;
    if(e>=E) return;
    int is64 = edge_is64(eidx);
    int d = edge_ld(eidx, is64, E+e);
    if((unsigned)d < (unsigned)N) atomicAdd(&deg[d], 1);
    return;
  }
  if(b < nbE + 256){
    int i = (b-nbE)*256 + threadIdx.x;
    int stride = 256*256;
    float m = 0.f;
    for(; i<N; i+=stride){
      float a = x[(size_t)i*12+3];
      float bb = x[(size_t)i*12+4];
      float c = x[(size_t)i*12+5];
      m = fmaxf(m, sqrtf(a*a+bb*bb+c*c));
    }
    #pragma unroll
    for(int off=1; off<64; off<<=1) m = fmaxf(m, __shfl_xor(m, off));
    if((threadIdx.x & 63)==0) atomicMax(ratio, __float_as_uint(m));
    return;
  }
  int idx = (b - nbE - 256)*256 + threadIdx.x;   // 196608 total
  int j = idx & 7;
  int lane = (idx>>3) & 63;
  int q = lane >> 4, p = lane & 15;
  if(idx < 131072){
    int nt = (idx>>9) & 7, ks = (idx>>12) & 7, l = (idx>>15) & 3;
    int k = ks*32 + q*8 + j, n = nt*16 + p;
    float v = (k<128) ? llW[(size_t)l*16384 + (size_t)k*128 + n]
                      : lrW[(size_t)l*16384 + (size_t)(k-128)*128 + n];
    WTs[idx] = (unsigned short)f2bf(v);
  } else if(idx < 163840){
    int i2 = idx - 131072;
    int nt = (i2>>9) & 15, ks = (i2>>13) & 3;
    int k = ks*32 + q*8 + j, n = nt*16 + p;
    float v = (n<128) ? dW1[(size_t)k*128 + n] : sW1[(size_t)k*128 + (n-128)];
    WT1[i2] = (unsigned short)f2bf(v);
  } else if(idx < 180224){
    int i2 = idx - 163840;
    int nt = (i2>>9) & 7, ks = (i2>>12) & 3;
    int k = ks*32 + q*8 + j, n = nt*16 + p;
    float v = (n<64) ? dW2[(size_t)k*64 + n] : sW2[(size_t)k*64 + (n-64)];
    WT2[i2] = (unsigned short)f2bf(v);
  } else if(idx < 196608){
    int i2 = idx - 180224;
    int nt = (i2>>9) & 7, ks = (i2>>12) & 3;
    int k = ks*32 + q*8 + j, n = nt*16 + p;
    WE2[i2] = (unsigned short)f2bf(eW2[(size_t)k*128 + n]);
  }
}

// ---------------- scan over deg[N] ----------------
__global__ void k_scan1(const int* __restrict__ deg, int* __restrict__ bsum, int N){
  int t = threadIdx.x;
  int idx0 = blockIdx.x*1024 + t*4;
  int s=0;
  #pragma unroll
  for(int i=0;i<4;i++){ int idx=idx0+i; if(idx<N) s += deg[idx]; }
  #pragma unroll
  for(int off=1; off<64; off<<=1) s += __shfl_xor(s, off);
  __shared__ int ws4[4];
  if((t&63)==0) ws4[t>>6]=s;
  __syncthreads();
  if(t==0) bsum[blockIdx.x]=ws4[0]+ws4[1]+ws4[2]+ws4[3];
}
// scan3 with inlined scan-of-block-sums (nb <= 64)
__global__ void k_scan3(const int* __restrict__ deg, const int* __restrict__ bsum,
                        int* __restrict__ offs, int* __restrict__ pos,
                        float* __restrict__ invdeg, int N, int E, int nb){
  __shared__ int sb[64];
  int t = threadIdx.x;
  if(t < 64){
    int v = (t<nb)? bsum[t] : 0;
    int incl = v;
    #pragma unroll
    for(int off=1; off<64; off<<=1){ int u = __shfl_up(incl, (unsigned)off); if(t>=off) incl+=u; }
    sb[t] = incl - v;   // exclusive
  }
  __syncthreads();
  int idx0 = blockIdx.x*1024 + t*4;
  int d[4]; int s=0;
  #pragma unroll
  for(int i=0;i<4;i++){ int idx=idx0+i; d[i] = (idx<N)? deg[idx]:0; s+=d[i]; }
  int lane=t&63, w=t>>6;
  int incl=s;
  #pragma unroll
  for(int off=1; off<64; off<<=1){ int v=__shfl_up(incl, (unsigned)off); if(lane>=off) incl+=v; }
  __shared__ int wsum[4];
  if(lane==63) wsum[w]=incl;
  __syncthreads();
  int base = sb[blockIdx.x];
  for(int i=0;i<w;i++) base += wsum[i];
  int run = base + incl - s;
  #pragma unroll
  for(int i=0;i<4;i++){
    int idx=idx0+i;
    if(idx<N){
      offs[idx]=run; pos[idx]=run;
      invdeg[idx] = 1.0f / (float)(d[i]>0? d[i]:1);
    }
    run += d[i];
  }
  if(blockIdx.x==0 && t==0) offs[N]=E;
}

// ---------------- encoder (blocks [0,nbTile)) + CSR bucket (rest), merged ----------
__global__ __launch_bounds__(256) void k_enc_bucket(
  const float* __restrict__ x,
  const float* __restrict__ W1, const float* __restrict__ b1,
  const unsigned short* __restrict__ WE2, const float* __restrict__ b2,
  bf16* __restrict__ h, int N, int nbTile,
  const int* __restrict__ eidx, int* __restrict__ pos, int* __restrict__ csr, int E)
{
  if((int)blockIdx.x >= nbTile){
    int e = ((int)blockIdx.x - nbTile)*256 + threadIdx.x;
    if(e>=E) return;
    int is64 = edge_is64(eidx);
    int d = edge_ld(eidx, is64, E+e);
    int s = edge_ld(eidx, is64, e);
    if((unsigned)d >= (unsigned)N) return;
    if((unsigned)s >= (unsigned)N) s = 0;
    int p = atomicAdd(&pos[d], 1);
    if((unsigned)p < (unsigned)E) csr[p] = s;
    return;
  }
  __shared__ float Xs[64][12];
  __shared__ float W1s[12][128];
  __shared__ float b1s[128];
  __shared__ __align__(16) unsigned short T1b[64][136];
  int tid = threadIdx.x;
  int tx = tid & 31, ty = tid >> 5;
  int rowBase = blockIdx.x*64;
  for(int idx=tid; idx<768; idx+=256){
    int r = idx/12, c = idx - r*12;
    int row = rowBase + r;
    Xs[r][c] = (row<N)? x[(size_t)row*12+c] : 0.f;
  }
  for(int idx=tid; idx<1536; idx+=256) W1s[idx>>7][idx&127] = W1[idx];
  if(tid<128) b1s[tid] = b1[tid];
  __syncthreads();
  float acc[8][4] = {};
  #pragma unroll
  for(int k=0;k<12;k++){
    float4 w4 = *(float4*)&W1s[k][tx*4];
    #pragma unroll
    for(int r=0;r<8;r++){
      float a = Xs[ty*8+r][k];
      acc[r][0]+=a*w4.x; acc[r][1]+=a*w4.y; acc[r][2]+=a*w4.z; acc[r][3]+=a*w4.w;
    }
  }
  #pragma unroll
  for(int r=0;r<8;r++)
    #pragma unroll
    for(int c=0;c<4;c++)
      T1b[ty*8+r][tx*4+c] = (unsigned short)f2bf(fmaxf(acc[r][c] + b1s[tx*4+c], 0.f));
  __syncthreads();

  int lane = tid & 63;
  int w = tid >> 6, q = lane >> 4, p = lane & 15;
  f32x4 acc2[8];
  #pragma unroll
  for(int nt=0; nt<8; nt++) acc2[nt] = (f32x4){0.f,0.f,0.f,0.f};
  #pragma unroll
  for(int ks=0; ks<4; ks++){
    bf16x8 af = *(const bf16x8*)&T1b[w*16+p][ks*32+q*8];
    #pragma unroll
    for(int nt=0; nt<8; nt++){
      bf16x8 bfr = *(const bf16x8*)(WE2 + ((size_t)(ks*8+nt)*64 + lane)*8);
      acc2[nt] = __builtin_amdgcn_mfma_f32_16x16x32_bf16(af, bfr, acc2[nt], 0,0,0);
    }
  }
  float b2v[8];
  #pragma unroll
  for(int nt=0; nt<8; nt++) b2v[nt] = b2[nt*16+p];
  unsigned short* hu = (unsigned short*)h;
  #pragma unroll
  for(int r=0;r<4;r++){
    int row = rowBase + w*16 + q*4 + r;
    if(row < N){
      #pragma unroll
      for(int nt=0; nt<8; nt++)
        hu[(size_t)row*128 + nt*16+p] = (unsigned short)f2bf(acc2[nt][r] + b2v[nt]);
    }
  }
}

// ---------------- fused SAGE layer, gather-shaped grid: 16 rows/block --------------
// (R11 champion) Phase 1: one quarter-wave per row, mean-aggregate into LDS.
// Phase 2: M=16 MFMA tile, cross-wave LDS LN reduction, residual, write hout.
__global__ __launch_bounds__(256) void k_layer16(
    const bf16* __restrict__ hin, bf16* __restrict__ hout,
    const int* __restrict__ offs, const int* __restrict__ csr,
    const float* __restrict__ invdeg,
    const unsigned short* __restrict__ WT,   // swizzled frags [ks8][nt8][64][8]
    const float* __restrict__ bl, const float* __restrict__ lng,
    const float* __restrict__ lnb, int N, int E)
{
  __shared__ __align__(16) unsigned short Ag[16][136];
  __shared__ float sPart[4][16];
  __shared__ float qPart[4][16];
  int tid = threadIdx.x;
  int rowBase = blockIdx.x*16;

  // ---- phase 1: gather-aggregate (quarter-wave per row, unroll-4) ----
  {
    int qw = tid >> 4;          // 0..15: local row
    int l  = tid & 15;          // 16 lanes x uint4 cover 128 cols
    int row = rowBase + qw;
    float a0=0.f,a1=0.f,a2=0.f,a3=0.f,a4=0.f,a5=0.f,a6=0.f,a7=0.f;
    if(row < N){
      int s = offs[row], e = offs[row+1];
      s = max(0, min(s, E)); e = max(s, min(e, E));
      int i = s;
      for(; i+4<=e; i+=4){
        int j0=csr[i], j1=csr[i+1], j2=csr[i+2], j3=csr[i+3];
        uint4 u0 = *(const uint4*)(hin + (size_t)j0*128 + l*8);
        uint4 u1 = *(const uint4*)(hin + (size_t)j1*128 + l*8);
        uint4 u2 = *(const uint4*)(hin + (size_t)j2*128 + l*8);
        uint4 u3 = *(const uint4*)(hin + (size_t)j3*128 + l*8);
        float2 f;
        f=bfpair(u0.x); a0+=f.x; a1+=f.y;  f=bfpair(u0.y); a2+=f.x; a3+=f.y;
        f=bfpair(u0.z); a4+=f.x; a5+=f.y;  f=bfpair(u0.w); a6+=f.x; a7+=f.y;
        f=bfpair(u1.x); a0+=f.x; a1+=f.y;  f=bfpair(u1.y); a2+=f.x; a3+=f.y;
        f=bfpair(u1.z); a4+=f.x; a5+=f.y;  f=bfpair(u1.w); a6+=f.x; a7+=f.y;
        f=bfpair(u2.x); a0+=f.x; a1+=f.y;  f=bfpair(u2.y); a2+=f.x; a3+=f.y;
        f=bfpair(u2.z); a4+=f.x; a5+=f.y;  f=bfpair(u2.w); a6+=f.x; a7+=f.y;
        f=bfpair(u3.x); a0+=f.x; a1+=f.y;  f=bfpair(u3.y); a2+=f.x; a3+=f.y;
        f=bfpair(u3.z); a4+=f.x; a5+=f.y;  f=bfpair(u3.w); a6+=f.x; a7+=f.y;
      }
      for(; i<e; ++i){
        int jj = csr[i];
        uint4 u = *(const uint4*)(hin + (size_t)jj*128 + l*8);
        float2 f;
        f=bfpair(u.x); a0+=f.x; a1+=f.y;  f=bfpair(u.y); a2+=f.x; a3+=f.y;
        f=bfpair(u.z); a4+=f.x; a5+=f.y;  f=bfpair(u.w); a6+=f.x; a7+=f.y;
      }
      float id = invdeg[row];
      a0*=id; a1*=id; a2*=id; a3*=id; a4*=id; a5*=id; a6*=id; a7*=id;
    }
    uint4 o;
    o.x = fpack(a0,a1); o.y = fpack(a2,a3);
    o.z = fpack(a4,a5); o.w = fpack(a6,a7);
    *(uint4*)&Ag[qw][l*8] = o;
  }
  __syncthreads();

  // ---- phase 2: y = [agg|hin] @ Wcat + bl ----
  int lane = tid & 63;
  int w = tid >> 6;            // wave 0..3 -> n-tiles 2w, 2w+1
  int q = lane >> 4;
  int p = lane & 15;
  int nt0 = 2*w, nt1 = 2*w+1;
  int am = rowBase + p;        // A-operand row for this lane
  bool ok = am < N;
  const unsigned short* hRow = (const unsigned short*)hin + (size_t)am*128;

  f32x4 accA = (f32x4){0.f,0.f,0.f,0.f};
  f32x4 accB = (f32x4){0.f,0.f,0.f,0.f};
  #pragma unroll
  for(int ks=0; ks<8; ks++){
    bf16x8 af;
    if(ks < 4){
      af = *(const bf16x8*)&Ag[p][ks*32 + q*8];
    } else {
      af = (bf16x8){0,0,0,0,0,0,0,0};
      if(ok) af = *(const bf16x8*)(hRow + (ks-4)*32 + q*8);
    }
    bf16x8 b0 = *(const bf16x8*)(WT + ((size_t)(ks*8+nt0)*64 + lane)*8);
    bf16x8 b1 = *(const bf16x8*)(WT + ((size_t)(ks*8+nt1)*64 + lane)*8);
    accA = __builtin_amdgcn_mfma_f32_16x16x32_bf16(af, b0, accA, 0,0,0);
    accB = __builtin_amdgcn_mfma_f32_16x16x32_bf16(af, b1, accB, 0,0,0);
  }

  // bias + per-wave partial LN sums (rows q*4+r, this wave's 32 cols)
  int c0 = nt0*16 + p, c1 = nt1*16 + p;
  float bl0 = bl[c0], g0 = lng[c0], lb0 = lnb[c0];
  float bl1 = bl[c1], g1 = lng[c1], lb1 = lnb[c1];
  float y0[4], y1[4];
  #pragma unroll
  for(int r=0;r<4;r++){
    y0[r] = accA[r] + bl0;
    y1[r] = accB[r] + bl1;
    float s  = y0[r] + y1[r];
    float sq = y0[r]*y0[r] + y1[r]*y1[r];
    #pragma unroll
    for(int off=1; off<16; off<<=1){ s += __shfl_xor(s, off); sq += __shfl_xor(sq, off); }
    if(p==0){ sPart[w][q*4+r] = s; qPart[w][q*4+r] = sq; }
  }
  __syncthreads();

  // totals, LN, residual-ReLU, store
  const unsigned short* hiu = (const unsigned short*)hin;
  unsigned short* hou = (unsigned short*)hout;
  #pragma unroll
  for(int r=0;r<4;r++){
    int rloc = q*4 + r;
    float s  = sPart[0][rloc]+sPart[1][rloc]+sPart[2][rloc]+sPart[3][rloc];
    float sq = qPart[0][rloc]+qPart[1][rloc]+qPart[2][rloc]+qPart[3][rloc];
    float mu = s*(1.f/128.f);
    float var = fmaxf(sq*(1.f/128.f) - mu*mu, 0.f);
    float rstd = rsqrtf(var + 1e-5f);
    int row = rowBase + rloc;
    if(row < N){
      float h0 = bfu(hiu[(size_t)row*128 + c0]);
      float h1 = bfu(hiu[(size_t)row*128 + c1]);
      float o0 = h0 + fmaxf((y0[r]-mu)*rstd*g0 + lb0, 0.f);
      float o1 = h1 + fmaxf((y1[r]-mu)*rstd*g1 + lb1, 0.f);
      hou[(size_t)row*128 + c0] = (unsigned short)f2bf(o0);
      hou[(size_t)row*128 + c1] = (unsigned short)f2bf(o1);
    }
  }
}

// ---------------- fused both-heads via MFMA, swizzled B frags ----------------
__global__ __launch_bounds__(256) void k_heads_mfma(
  const bf16* __restrict__ h,
  const unsigned short* __restrict__ WT1,  // [ks4][nt16][64][8]
  const unsigned short* __restrict__ WT2,  // [ks4][nt8][64][8]
  const float* __restrict__ db1, const float* __restrict__ sb1,
  const float* __restrict__ db2, const float* __restrict__ sb2,
  const float* __restrict__ dW3, const float* __restrict__ db3,
  const float* __restrict__ sW3, const float* __restrict__ sb3,
  const float* __restrict__ ratio_p, float* __restrict__ out, int N)
{
  __shared__ __align__(16) unsigned short T1s[4][16][264];
  const float ratio = *ratio_p;
  int tid = threadIdx.x;
  int lane = tid & 63;
  int w = tid >> 6;
  int q = lane >> 4;
  int p = lane & 15;
  int rowBase = blockIdx.x*64;
  int am = rowBase + w*16 + p;
  bool arow_ok = am < N;
  const unsigned short* hRow = (const unsigned short*)h + (size_t)am*128;

  f32x4 acc1[16];
  #pragma unroll
  for(int nt=0; nt<16; nt++) acc1[nt] = (f32x4){0.f,0.f,0.f,0.f};
  #pragma unroll
  for(int ks=0; ks<4; ks++){
    int koff = ks*32 + q*8;
    bf16x8 af = {0,0,0,0,0,0,0,0};
    if(arow_ok) af = *(const bf16x8*)(hRow + koff);
    #pragma unroll
    for(int nt=0; nt<16; nt++){
      bf16x8 bfr = *(const bf16x8*)(WT1 + ((size_t)(ks*16+nt)*64 + lane)*8);
      acc1[nt] = __builtin_amdgcn_mfma_f32_16x16x32_bf16(af, bfr, acc1[nt], 0,0,0);
    }
  }
  #pragma unroll
  for(int nt=0; nt<16; nt++){
    float b1v = (nt<8) ? db1[nt*16+p] : sb1[(nt-8)*16+p];
    #pragma unroll
    for(int r=0;r<4;r++){
      float v = fmaxf(acc1[nt][r] + b1v, 0.f);
      T1s[w][q*4+r][nt*16+p] = (unsigned short)f2bf(v);
    }
  }
  __syncthreads();

  f32x4 acc2[8];
  #pragma unroll
  for(int nt=0; nt<8; nt++) acc2[nt] = (f32x4){0.f,0.f,0.f,0.f};
  #pragma unroll
  for(int ks=0; ks<4; ks++){
    int koff = ks*32 + q*8;
    bf16x8 ad = *(const bf16x8*)&T1s[w][p][koff];
    bf16x8 as = *(const bf16x8*)&T1s[w][p][128+koff];
    #pragma unroll
    for(int nt=0; nt<8; nt++){
      bf16x8 bfr = *(const bf16x8*)(WT2 + ((size_t)(ks*8+nt)*64 + lane)*8);
      acc2[nt] = __builtin_amdgcn_mfma_f32_16x16x32_bf16(nt<4? ad : as, bfr, acc2[nt], 0,0,0);
    }
  }

  float w3d[4][3], w3s[4], bd2[4], bs2[4];
  #pragma unroll
  for(int nt=0; nt<4; nt++){
    #pragma unroll
    for(int c=0;c<3;c++) w3d[nt][c] = dW3[(nt*16+p)*3 + c];
    w3s[nt] = sW3[nt*16+p];
    bd2[nt] = db2[nt*16+p];
    bs2[nt] = sb2[nt*16+p];
  }
  float b3v = (p==0)? db3[0] : (p==1)? db3[1] : (p==2)? db3[2] : sb3[0];
  #pragma unroll
  for(int r=0;r<4;r++){
    int row = rowBase + w*16 + q*4 + r;
    float pd0=0.f, pd1=0.f, pd2=0.f, ps=0.f;
    #pragma unroll
    for(int nt=0; nt<4; nt++){
      float td = fmaxf(acc2[nt][r]   + bd2[nt], 0.f);
      float ts = fmaxf(acc2[nt+4][r] + bs2[nt], 0.f);
      pd0 += td*w3d[nt][0]; pd1 += td*w3d[nt][1]; pd2 += td*w3d[nt][2];
      ps  += ts*w3s[nt];
    }
    #pragma unroll
    for(int off=1; off<16; off<<=1){
      pd0 += __shfl_xor(pd0, off); pd1 += __shfl_xor(pd1, off);
      pd2 += __shfl_xor(pd2, off); ps  += __shfl_xor(ps, off);
    }
    if(row < N && p < 4){
      float v = (p==0)? pd0 : (p==1)? pd1 : (p==2)? pd2 : ps;
      out[(size_t)row*4 + p] = (v + b3v)*ratio;
    }
  }
}

extern "C" void kernel_launch(void* const* d_in, const int* in_sizes, int n_in,
                              void* d_out, int out_size, void* d_ws, size_t ws_size,
                              hipStream_t stream)
{
  const float* x   = (const float*)d_in[0];
  const int*  eidx = (const int*) d_in[1];
  const float* eW1 = (const float*)d_in[2];
  const float* eb1 = (const float*)d_in[3];
  const float* eW2 = (const float*)d_in[4];
  const float* eb2 = (const float*)d_in[5];
  const float* llW = (const float*)d_in[6];
  const float* llb = (const float*)d_in[7];
  const float* lrW = (const float*)d_in[8];
  const float* lng = (const float*)d_in[9];
  const float* lnb = (const float*)d_in[10];
  const float* dW1 = (const float*)d_in[11];
  const float* db1 = (const float*)d_in[12];
  const float* dW2 = (const float*)d_in[13];
  const float* db2 = (const float*)d_in[14];
  const float* dW3 = (const float*)d_in[15];
  const float* db3 = (const float*)d_in[16];
  const float* sW1 = (const float*)d_in[17];
  const float* sb1 = (const float*)d_in[18];
  const float* sW2 = (const float*)d_in[19];
  const float* sb2 = (const float*)d_in[20];
  const float* sW3 = (const float*)d_in[21];
  const float* sb3 = (const float*)d_in[22];
  float* out = (float*)d_out;

  const int N = in_sizes[0] / 12;
  const int E = in_sizes[1] / 2;
  (void)n_in; (void)out_size; (void)ws_size;

  char* base = (char*)d_ws;
  size_t off = 0;
  auto alloc = [&](size_t nbytes)->char*{
    char* p = base + off; off += (nbytes + 255) & ~(size_t)255; return p;
  };
  unsigned* ratio = (unsigned*)alloc(4);
  int*   deg    = (int*)  alloc((size_t)N*4);
  int*   offs   = (int*)  alloc(((size_t)N+1)*4);
  int*   pos    = (int*)  alloc((size_t)N*4);
  int*   bsum   = (int*)  alloc(256*4);
  int*   csr    = (int*)  alloc((size_t)E*4);
  float* invdeg = (float*)alloc((size_t)N*4);
  bf16*  hA     = (bf16*) alloc((size_t)N*128*2);
  bf16*  hB     = (bf16*) alloc((size_t)N*128*2);
  unsigned short* WTs  = (unsigned short*)alloc((size_t)131072*2);
  unsigned short* WT1h = (unsigned short*)alloc((size_t)32768*2);
  unsigned short* WT2h = (unsigned short*)alloc((size_t)16384*2);
  unsigned short* WE2  = (unsigned short*)alloc((size_t)16384*2);

  size_t zbytes = (size_t)((char*)offs - base);   // zero ratio + deg
  hipMemsetAsync(d_ws, 0, zbytes, stream);

  int nbE    = (E + 255)/256;
  int nbScan = (N + 1023)/1024;
  int nbTile = (N + 63)/64;
  int nbLay  = (N + 15)/16;

  k_pre  <<<nbE + 256 + 768, 256, 0, stream>>>(x, eidx, ratio, deg, N, E, nbE,
      llW, lrW, dW1, sW1, dW2, sW2, eW2, WTs, WT1h, WT2h, WE2);
  k_scan1<<<nbScan, 256, 0, stream>>>(deg, bsum, N);
  k_scan3<<<nbScan, 256, 0, stream>>>(deg, bsum, offs, pos, invdeg, N, E, nbScan);
  k_enc_bucket<<<nbTile + nbE, 256, 0, stream>>>(x, eW1, eb1, WE2, eb2, hA, N, nbTile,
      eidx, pos, csr, E);

  bf16* hin = hA; bf16* hout = hB;
  for(int l=0;l<4;l++){
    k_layer16<<<nbLay, 256, 0, stream>>>(hin, hout, offs, csr, invdeg,
        WTs + (size_t)l*32768,
        llb + (size_t)l*128, lng + (size_t)l*128, lnb + (size_t)l*128, N, E);
    bf16* t = hin; hin = hout; hout = t;
  }
  // after 4 swaps, final h is in hA (hin)
  k_heads_mfma<<<nbTile, 256, 0, stream>>>(hin, WT1h, WT2h,
      db1, sb1, db2, sb2, dW3, db3, sW3, sb3, (const float*)ratio, out, N);
}